// Round 4
// baseline (290.036 us; speedup 1.0000x reference)
//
#include <hip/hip_runtime.h>

// Causal attention fwd, B=2 H=16 S=2048 DK=DV=64, fp32 in/out.
// R4: parallelism round. Q_TILE=64 (grid 1024 = 32bh x 32qt, big-first),
// 4 waves = 2 q-halves x 2 kv-parities (kv-split-2) over a 128-kv superstep
// staged in 32KB single-buffered LDS with issue-early/commit-late (T14).
// End-of-block (m,l,O) merge via LDS. __launch_bounds__(256,4) -> 4 waves/SIMD.

#define S_LEN   2048
#define D_DIM   64
#define BH_N    32
#define NEG_BIG (-3.0e38f)
#define CSCALE  0.18033688011112042f   // log2(e)/sqrt(64)

typedef float     f32x16 __attribute__((ext_vector_type(16)));
typedef _Float16  f16x8  __attribute__((ext_vector_type(8)));
typedef __fp16    fp16x2 __attribute__((ext_vector_type(2)));
typedef unsigned int   u32;
typedef unsigned short u16;

__device__ __forceinline__ u32 pkrtz2(float a, float b) {
  union { fp16x2 h; u32 u; } U;
  U.h = __builtin_amdgcn_cvt_pkrtz(a, b);
  return U.u;
}

__device__ __forceinline__ void plswap(u32& a, u32& b) {
  auto r = __builtin_amdgcn_permlane32_swap((int)a, (int)b, false, false);
  a = (u32)r[0]; b = (u32)r[1];
}

__device__ __forceinline__ f32x16 mfma16(f16x8 a, f16x8 b, f32x16 c) {
  return __builtin_amdgcn_mfma_f32_32x32x16_f16(a, b, c, 0, 0, 0);
}

// K tile: [128 kv][64 d] f16, 128B rows, 3-bit XOR swizzle
__device__ __forceinline__ f16x8 lds_fragK(const u16* base, int row, int colByte) {
  u32 off = (u32)(row * 128 + colByte);
  off ^= ((u32)(row & 7)) << 4;
  return *(const f16x8*)((const char*)base + off);
}
// V^T tile: [64 dv][128 kv] f16, 256B rows, 4-bit XOR swizzle
__device__ __forceinline__ f16x8 lds_fragV(const u16* base, int row, int colByte) {
  u32 off = (u32)(row * 256 + colByte);
  off ^= ((u32)(row & 15)) << 4;
  return *(const f16x8*)((const char*)base + off);
}

// ---------------- prep: V[bh][kv][dv] f32 -> Vt[bh][dv][kv] f16 ----------------
__global__ __launch_bounds__(256) void vtrans_kernel(const float* __restrict__ V,
                                                     u16* __restrict__ Vt) {
  __shared__ __align__(16) float buf[64 * 64];   // swizzled: byte ^= ((r>>3)&6)<<4
  const int bid = blockIdx.x;          // 1024 = 32 bh * 32 kv-tiles
  const int bh  = bid & (BH_N - 1);
  const int kv0 = (bid >> 5) * 64;
  const int t   = threadIdx.x;
  {
    const int r = t >> 2, c0 = (t & 3) * 16;
    const float* src = V + ((size_t)bh * S_LEN + kv0 + r) * D_DIM + c0;
    const u32 swz = ((u32)((r >> 3) & 6)) << 4;
    #pragma unroll
    for (int k = 0; k < 4; ++k) {
      float4 a = *(const float4*)(src + 4 * k);
      *(float4*)((char*)buf + (((u32)(r * 256 + (c0 + 4 * k) * 4)) ^ swz)) = a;
    }
  }
  __syncthreads();
  {
    const int dv = t >> 2, kc = (t & 3) * 16;
    u32 w[8];
    #pragma unroll
    for (int j = 0; j < 8; ++j) {
      const int r0 = kc + 2 * j, r1 = kc + 2 * j + 1;
      float x0 = *(const float*)((char*)buf +
                 (((u32)(r0 * 256 + dv * 4)) ^ (((u32)((r0 >> 3) & 6)) << 4)));
      float x1 = *(const float*)((char*)buf +
                 (((u32)(r1 * 256 + dv * 4)) ^ (((u32)((r1 >> 3) & 6)) << 4)));
      w[j] = pkrtz2(x0, x1);
    }
    u16* dst = Vt + ((size_t)bh * D_DIM + dv) * S_LEN + kv0 + kc;
    *(uint4*)(dst + 0) = make_uint4(w[0], w[1], w[2], w[3]);
    *(uint4*)(dst + 8) = make_uint4(w[4], w[5], w[6], w[7]);
  }
}

// ---------------- main flash attention ----------------
__global__ __launch_bounds__(256, 4) void attn_kernel(const float* __restrict__ Q,
                                                      const float* __restrict__ K,
                                                      const u16* __restrict__ Vt,
                                                      float* __restrict__ Out) {
  __shared__ __align__(16) u16 KS[128 * 64];   // 16KB: kv-major K tile (128 kv)
  __shared__ __align__(16) u16 VS[64 * 128];   // 16KB: V^T tile (128 kv cols)

  const int bid = blockIdx.x;          // 1024 = 32 bh * 32 qt
  const int bh  = bid & 31;
  const int qt  = 31 - (bid >> 5);     // biggest causal jobs first
  const int t   = threadIdx.x;
  const int w   = t >> 6;
  const int lo31 = t & 31;
  const int hi  = (t >> 5) & 1;
  const int p   = w >> 1;              // kv parity: waves 0,1 -> even tiles; 2,3 -> odd
  const int qb  = qt * 64 + (w & 1) * 32;

  // Q fragment (f16, scale folded): col=q=lane&31, k=d = kk*16 + hi*8 + j
  f16x8 qf[4];
  {
    const float* qp = Q + ((size_t)bh * S_LEN + qb + lo31) * D_DIM;
    #pragma unroll
    for (int kk = 0; kk < 4; ++kk) {
      const int dd = kk * 16 + hi * 8;
      float4 a = *(const float4*)(qp + dd);
      float4 b = *(const float4*)(qp + dd + 4);
      union { u32 u[4]; f16x8 v; } U;
      U.u[0] = pkrtz2(a.x * CSCALE, a.y * CSCALE);
      U.u[1] = pkrtz2(a.z * CSCALE, a.w * CSCALE);
      U.u[2] = pkrtz2(b.x * CSCALE, b.y * CSCALE);
      U.u[3] = pkrtz2(b.z * CSCALE, b.w * CSCALE);
      qf[kk] = U.v;
    }
  }

  f32x16 o0 = {};      // O^T rows dv 0..31 (col=q, row=(i&3)+8*(i>>2)+4*hi)
  f32x16 o1 = {};      // O^T rows dv 32..63
  float m_run = NEG_BIG;
  float r_sum = 0.0f;

  // staging: 128-kv superstep; K: 1 row/thread (64 f32), V: 32 f16/thread
  const int srK = t >> 1;              // 0..127
  const int scK = (t & 1) * 32;        // f32 col
  const int dvV = t >> 2;              // 0..63
  const int kqV = (t & 3) * 32;        // kv elem within superstep
  float4 kr[8];
  uint4  vr[4];

  auto issue = [&](int s) {
    const int kb128 = s * 128;
    const float* kg = K + ((size_t)bh * S_LEN + kb128 + srK) * D_DIM + scK;
    #pragma unroll
    for (int i = 0; i < 8; ++i) kr[i] = *(const float4*)(kg + 4 * i);
    const u16* vg = Vt + ((size_t)bh * D_DIM + dvV) * S_LEN + kb128 + kqV;
    #pragma unroll
    for (int i = 0; i < 4; ++i) vr[i] = *(const uint4*)(vg + 8 * i);
  };
  auto commit = [&]() {
    const u32 kbase = (u32)(srK * 128 + scK * 2);
    const u32 ksw   = ((u32)(srK & 7)) << 4;
    #pragma unroll
    for (int c = 0; c < 4; ++c) {
      uint4 d = make_uint4(pkrtz2(kr[2*c].x, kr[2*c].y),  pkrtz2(kr[2*c].z, kr[2*c].w),
                           pkrtz2(kr[2*c+1].x, kr[2*c+1].y), pkrtz2(kr[2*c+1].z, kr[2*c+1].w));
      *(uint4*)((char*)KS + ((kbase + 16 * c) ^ ksw)) = d;
    }
    const u32 vbase = (u32)(dvV * 256 + kqV * 2);
    const u32 vsw   = ((u32)(dvV & 15)) << 4;
    #pragma unroll
    for (int c = 0; c < 4; ++c)
      *(uint4*)((char*)VS + ((vbase + 16 * c) ^ vsw)) = vr[c];
  };

  const int NT = qt + 1;               // 64-kv tiles
  const int NS = (NT + 1) >> 1;        // 128-kv supersteps

  issue(0);
  commit();
  __syncthreads();

  for (int s = 0; s < NS; ++s) {
    if (s + 1 < NS) issue(s + 1);      // hide HBM under compute (T14)

    const int kb = (2 * s + p) * 64;   // this wave-pair's tile
    if (kb <= qb) {
      const bool have1 = (kb + 32 <= qb);
      const bool dg0   = (kb == qb);
      const bool dg1   = (kb + 32 == qb);

      f32x16 s0 = {}, s1 = {};
      __builtin_amdgcn_s_setprio(1);
      #pragma unroll
      for (int kk = 0; kk < 4; ++kk) {
        f16x8 kf = lds_fragK(KS, p * 64 + lo31, kk * 32 + hi * 16);
        s0 = mfma16(kf, qf[kk], s0);
      }
      if (have1) {
        #pragma unroll
        for (int kk = 0; kk < 4; ++kk) {
          f16x8 kf = lds_fragK(KS, p * 64 + 32 + lo31, kk * 32 + hi * 16);
          s1 = mfma16(kf, qf[kk], s1);
        }
      }
      __builtin_amdgcn_s_setprio(0);

      if (dg0) {
        #pragma unroll
        for (int i = 0; i < 16; ++i) {
          const int kvloc = (i & 3) + 8 * (i >> 2) + 4 * hi;
          if (kvloc > lo31) s0[i] = NEG_BIG;
        }
      }
      if (have1 && dg1) {
        #pragma unroll
        for (int i = 0; i < 16; ++i) {
          const int kvloc = (i & 3) + 8 * (i >> 2) + 4 * hi;
          if (kvloc > lo31) s1[i] = NEG_BIG;
        }
      }

      // --- 64-wide online softmax (lane pair l, l+32 = one q-row) ---
      float t8[8];
      #pragma unroll
      for (int i = 0; i < 8; ++i) t8[i] = fmaxf(s0[i], s0[i + 8]);
      if (have1) {
        #pragma unroll
        for (int i = 0; i < 8; ++i) t8[i] = fmaxf(t8[i], fmaxf(s1[i], s1[i + 8]));
      }
      float t4a = fmaxf(t8[0], t8[4]), t4b = fmaxf(t8[1], t8[5]);
      float t4c = fmaxf(t8[2], t8[6]), t4d = fmaxf(t8[3], t8[7]);
      float mt = fmaxf(fmaxf(t4a, t4b), fmaxf(t4c, t4d));
      mt = fmaxf(mt, __shfl_xor(mt, 32, 64));

      if (!__all(mt <= m_run + 8.0f)) {        // defer-max (T13)
        const float mn = fmaxf(m_run, mt);
        const float rs = __builtin_amdgcn_exp2f(m_run - mn);
        m_run = mn;
        r_sum *= rs;
        #pragma unroll
        for (int i = 0; i < 16; ++i) { o0[i] *= rs; o1[i] *= rs; }
      }

      float psum = 0.0f;
      u32 c0w[8], c1w[8];
      #pragma unroll
      for (int j = 0; j < 8; ++j) {
        float pa = __builtin_amdgcn_exp2f(s0[2 * j]     - m_run);
        float pb = __builtin_amdgcn_exp2f(s0[2 * j + 1] - m_run);
        psum += pa + pb;
        c0w[j] = pkrtz2(pa, pb);
      }
      if (have1) {
        #pragma unroll
        for (int j = 0; j < 8; ++j) {
          float pa = __builtin_amdgcn_exp2f(s1[2 * j]     - m_run);
          float pb = __builtin_amdgcn_exp2f(s1[2 * j + 1] - m_run);
          psum += pa + pb;
          c1w[j] = pkrtz2(pa, pb);
        }
      }
      psum += __shfl_xor(psum, 32, 64);
      r_sum += psum;

      // repack P (C/D layout) -> PV B-frags via permlane32_swap (T12)
      plswap(c0w[0], c0w[2]); plswap(c0w[1], c0w[3]);
      plswap(c0w[4], c0w[6]); plswap(c0w[5], c0w[7]);
      union { u32 u[4]; f16x8 v; } B0, B1;
      B0.u[0] = c0w[0]; B0.u[1] = c0w[1]; B0.u[2] = c0w[2]; B0.u[3] = c0w[3];
      B1.u[0] = c0w[4]; B1.u[1] = c0w[5]; B1.u[2] = c0w[6]; B1.u[3] = c0w[7];

      __builtin_amdgcn_s_setprio(1);
      #pragma unroll
      for (int ks = 0; ks < 2; ++ks) {
        f16x8 va = lds_fragV(VS, lo31,      p * 128 + ks * 32 + hi * 16);
        f16x8 vb = lds_fragV(VS, 32 + lo31, p * 128 + ks * 32 + hi * 16);
        f16x8 pf = (ks == 0) ? B0.v : B1.v;
        o0 = mfma16(va, pf, o0);
        o1 = mfma16(vb, pf, o1);
      }
      __builtin_amdgcn_s_setprio(0);

      if (have1) {
        plswap(c1w[0], c1w[2]); plswap(c1w[1], c1w[3]);
        plswap(c1w[4], c1w[6]); plswap(c1w[5], c1w[7]);
        union { u32 u[4]; f16x8 v; } B2, B3;
        B2.u[0] = c1w[0]; B2.u[1] = c1w[1]; B2.u[2] = c1w[2]; B2.u[3] = c1w[3];
        B3.u[0] = c1w[4]; B3.u[1] = c1w[5]; B3.u[2] = c1w[6]; B3.u[3] = c1w[7];
        __builtin_amdgcn_s_setprio(1);
        #pragma unroll
        for (int ks = 0; ks < 2; ++ks) {
          f16x8 va = lds_fragV(VS, lo31,      p * 128 + 64 + ks * 32 + hi * 16);
          f16x8 vb = lds_fragV(VS, 32 + lo31, p * 128 + 64 + ks * 32 + hi * 16);
          f16x8 pf = (ks == 0) ? B2.v : B3.v;
          o0 = mfma16(va, pf, o0);
          o1 = mfma16(vb, pf, o1);
        }
        __builtin_amdgcn_s_setprio(0);
      }
    }

    __syncthreads();                   // all waves done reading LDS
    if (s + 1 < NS) { commit(); __syncthreads(); }
  }

  // ---- merge kv-parity partials: wave w (p=1) -> LDS, wave w-2 (p=0) merges ----
  const int l64 = t & 63;
  if (p == 1) {
    float* mb = (float*)((w == 2) ? (void*)KS : (void*)VS);
    #pragma unroll
    for (int i = 0; i < 16; ++i) mb[i * 64 + l64] = o0[i];
    #pragma unroll
    for (int i = 0; i < 16; ++i) mb[(16 + i) * 64 + l64] = o1[i];
    mb[32 * 64 + l64] = m_run;
    mb[33 * 64 + l64] = r_sum;
  }
  __syncthreads();
  if (p == 0) {
    const float* mb = (const float*)((w == 0) ? (void*)KS : (void*)VS);
    const float m_b = mb[32 * 64 + l64];
    const float r_b = mb[33 * 64 + l64];
    const float mn  = fmaxf(m_run, m_b);
    const float sa  = __builtin_amdgcn_exp2f(m_run - mn);
    const float sb  = __builtin_amdgcn_exp2f(m_b  - mn);
    const float inv = 1.0f / (r_sum * sa + r_b * sb);
    float* op = Out + ((size_t)bh * S_LEN + qb + lo31) * D_DIM;
    #pragma unroll
    for (int g = 0; g < 4; ++g) {
      float4 s0v, s1v;
      #pragma unroll
      for (int k = 0; k < 4; ++k) {
        const int i = 4 * g + k;
        ((float*)&s0v)[k] = (o0[i] * sa + mb[i * 64 + l64]        * sb) * inv;
        ((float*)&s1v)[k] = (o1[i] * sa + mb[(16 + i) * 64 + l64] * sb) * inv;
      }
      *(float4*)(op + g * 8 + hi * 4)      = s0v;   // dv = 8g + 4*hi + 0..3
      *(float4*)(op + 32 + g * 8 + hi * 4) = s1v;   // dv + 32
    }
  }
}

extern "C" void kernel_launch(void* const* d_in, const int* in_sizes, int n_in,
                              void* d_out, int out_size, void* d_ws, size_t ws_size,
                              hipStream_t stream) {
  const float* Q = (const float*)d_in[0];
  const float* K = (const float*)d_in[1];
  const float* V = (const float*)d_in[2];
  // d_in[3] = tril mask: handled analytically (causal), not read.
  float* Out = (float*)d_out;
  u16* Vt = (u16*)d_ws;                       // 32*64*2048*2 B = 8.39 MB
  vtrans_kernel<<<dim3(BH_N * (S_LEN / 64)), dim3(256), 0, stream>>>(V, Vt);
  attn_kernel<<<dim3(BH_N * 32), dim3(256), 0, stream>>>(Q, K, Vt, Out);
}

// Round 5
// 218.966 us; speedup vs baseline: 1.3246x; 1.3246x over previous
//
#include <hip/hip_runtime.h>

// Causal attention fwd, B=2 H=16 S=2048 DK=DV=64, fp32 in/out.
// R5: fix R4's scratch-spill (203MB writes). Prep converts BOTH K->f16 (Kt)
// and V->V^T f16 (Vt) into d_ws; main loop stages pure f16 (32 staging VGPR),
// launch_bounds(256,3) (no forced spill), bank-conflict-free LDS packings.
// Structure kept from R4: grid 1024 (32bh x 32qt big-first), 4 waves =
// 2 q-subtiles x 2 kv-parities over 128-kv supersteps, end-of-block merge.

#define S_LEN   2048
#define D_DIM   64
#define BH_N    32
#define NEG_BIG (-3.0e38f)
#define CSCALE  0.18033688011112042f   // log2(e)/sqrt(64)

typedef float     f32x16 __attribute__((ext_vector_type(16)));
typedef _Float16  f16x8  __attribute__((ext_vector_type(8)));
typedef __fp16    fp16x2 __attribute__((ext_vector_type(2)));
typedef unsigned int   u32;
typedef unsigned short u16;

__device__ __forceinline__ u32 pkrtz2(float a, float b) {
  union { fp16x2 h; u32 u; } U;
  U.h = __builtin_amdgcn_cvt_pkrtz(a, b);
  return U.u;
}

__device__ __forceinline__ void plswap(u32& a, u32& b) {
  auto r = __builtin_amdgcn_permlane32_swap((int)a, (int)b, false, false);
  a = (u32)r[0]; b = (u32)r[1];
}

__device__ __forceinline__ f32x16 mfma16(f16x8 a, f16x8 b, f32x16 c) {
  return __builtin_amdgcn_mfma_f32_32x32x16_f16(a, b, c, 0, 0, 0);
}

// K tile: 128 kv x 64 d f16. LDS rows of 256B = kv pair (2R, 2R+1).
// chunk ci = (dchunk*2 + (kv&1)) ^ ((R&7)<<1)  -> octet-conflict-free R/W.
__device__ __forceinline__ f16x8 lds_fragK(const u16* base, int kv, int dchunk) {
  const u32 R  = (u32)kv >> 1;
  const u32 ci = ((u32)dchunk * 2 + ((u32)kv & 1)) ^ ((R & 7) << 1);
  return *(const f16x8*)((const char*)base + R * 256 + ci * 16);
}
// V^T tile: 64 dv x 128 kv f16, 256B rows. chunk ci = kvchunk ^ (dv&15).
__device__ __forceinline__ f16x8 lds_fragV(const u16* base, int dv, int kvchunk) {
  const u32 ci = (u32)kvchunk ^ ((u32)dv & 15);
  return *(const f16x8*)((const char*)base + (u32)dv * 256 + ci * 16);
}

// -------- prep: Kt[bh][kv][d] f16 (straight cvt) + Vt[bh][dv][kv] f16 --------
__global__ __launch_bounds__(256) void prep_kernel(const float* __restrict__ K,
                                                   const float* __restrict__ V,
                                                   u16* __restrict__ Kt,
                                                   u16* __restrict__ Vt) {
  __shared__ __align__(16) float buf[64 * 64];   // swizzled: byte ^= ((r>>3)&6)<<4
  const int bid = blockIdx.x;          // 1024 = 32 bh * 32 kv-tiles
  const int bh  = bid & (BH_N - 1);
  const int kv0 = (bid >> 5) * 64;
  const int t   = threadIdx.x;
  const int r   = t >> 2, c0 = (t & 3) * 16;
  { // K -> Kt (elementwise cvt, coalesced)
    const float* src = K + ((size_t)bh * S_LEN + kv0 + r) * D_DIM + c0;
    float4 a0 = *(const float4*)(src + 0);
    float4 a1 = *(const float4*)(src + 4);
    float4 a2 = *(const float4*)(src + 8);
    float4 a3 = *(const float4*)(src + 12);
    u16* dst = Kt + ((size_t)bh * S_LEN + kv0 + r) * D_DIM + c0;
    *(uint4*)(dst + 0) = make_uint4(pkrtz2(a0.x, a0.y), pkrtz2(a0.z, a0.w),
                                    pkrtz2(a1.x, a1.y), pkrtz2(a1.z, a1.w));
    *(uint4*)(dst + 8) = make_uint4(pkrtz2(a2.x, a2.y), pkrtz2(a2.z, a2.w),
                                    pkrtz2(a3.x, a3.y), pkrtz2(a3.z, a3.w));
  }
  { // V -> LDS (swizzled)
    const float* src = V + ((size_t)bh * S_LEN + kv0 + r) * D_DIM + c0;
    const u32 swz = ((u32)((r >> 3) & 6)) << 4;
    #pragma unroll
    for (int k = 0; k < 4; ++k) {
      float4 a = *(const float4*)(src + 4 * k);
      *(float4*)((char*)buf + (((u32)(r * 256 + (c0 + 4 * k) * 4)) ^ swz)) = a;
    }
  }
  __syncthreads();
  { // LDS -> Vt (transposed, cvt)
    const int dv = t >> 2, kc = (t & 3) * 16;
    u32 w[8];
    #pragma unroll
    for (int j = 0; j < 8; ++j) {
      const int r0 = kc + 2 * j, r1 = kc + 2 * j + 1;
      float x0 = *(const float*)((char*)buf +
                 (((u32)(r0 * 256 + dv * 4)) ^ (((u32)((r0 >> 3) & 6)) << 4)));
      float x1 = *(const float*)((char*)buf +
                 (((u32)(r1 * 256 + dv * 4)) ^ (((u32)((r1 >> 3) & 6)) << 4)));
      w[j] = pkrtz2(x0, x1);
    }
    u16* dst = Vt + ((size_t)bh * D_DIM + dv) * S_LEN + kv0 + kc;
    *(uint4*)(dst + 0) = make_uint4(w[0], w[1], w[2], w[3]);
    *(uint4*)(dst + 8) = make_uint4(w[4], w[5], w[6], w[7]);
  }
}

// ---------------- main flash attention ----------------
__global__ __launch_bounds__(256, 3) void attn_kernel(const float* __restrict__ Q,
                                                      const u16* __restrict__ Kt,
                                                      const u16* __restrict__ Vt,
                                                      float* __restrict__ Out) {
  __shared__ __align__(16) u16 KS[128 * 64];   // 16KB K tile (128 kv, packed pairs)
  __shared__ __align__(16) u16 VS[64 * 128];   // 16KB V^T tile (128 kv cols)

  const int bid = blockIdx.x;          // 1024 = 32 bh * 32 qt
  const int bh  = bid & 31;
  const int qt  = 31 - (bid >> 5);     // biggest causal jobs first
  const int t   = threadIdx.x;
  const int w   = t >> 6;
  const int lo31 = t & 31;
  const int hi  = (t >> 5) & 1;
  const int p   = w >> 1;              // kv parity: waves 0,1 even tiles; 2,3 odd
  const int qb  = qt * 64 + (w & 1) * 32;

  // Q fragment (f16, scale folded): col=q=lane&31, k=d = kk*16 + hi*8 + j
  f16x8 qf[4];
  {
    const float* qp = Q + ((size_t)bh * S_LEN + qb + lo31) * D_DIM;
    #pragma unroll
    for (int kk = 0; kk < 4; ++kk) {
      const int dd = kk * 16 + hi * 8;
      float4 a = *(const float4*)(qp + dd);
      float4 b = *(const float4*)(qp + dd + 4);
      union { u32 u[4]; f16x8 v; } U;
      U.u[0] = pkrtz2(a.x * CSCALE, a.y * CSCALE);
      U.u[1] = pkrtz2(a.z * CSCALE, a.w * CSCALE);
      U.u[2] = pkrtz2(b.x * CSCALE, b.y * CSCALE);
      U.u[3] = pkrtz2(b.z * CSCALE, b.w * CSCALE);
      qf[kk] = U.v;
    }
  }

  f32x16 o0 = {};      // O^T rows dv 0..31 (col=q, row=(i&3)+8*(i>>2)+4*hi)
  f32x16 o1 = {};      // O^T rows dv 32..63
  float m_run = NEG_BIG;
  float r_sum = 0.0f;

  // staging (all f16): K: kv = t&127, dhalf = t>>7 (64B); V: dv = t&63, kq = (t>>6)*32
  const int kvS = t & 127;
  const int dhS = t >> 7;
  const int dvS = t & 63;
  const int kqS = (t >> 6) & 3;        // which 32-kv quarter
  uint4 sk[4], sv[4];

  auto issue = [&](int s) {
    const int kb128 = s * 128;
    const u16* kg = Kt + ((size_t)bh * S_LEN + kb128 + kvS) * D_DIM + dhS * 32;
    #pragma unroll
    for (int i = 0; i < 4; ++i) sk[i] = *(const uint4*)(kg + 8 * i);
    const u16* vg = Vt + ((size_t)bh * D_DIM + dvS) * S_LEN + kb128 + kqS * 32;
    #pragma unroll
    for (int i = 0; i < 4; ++i) sv[i] = *(const uint4*)(vg + 8 * i);
  };
  auto commit = [&]() {
    const u32 R   = (u32)kvS >> 1;
    const u32 par = (u32)kvS & 1;
    #pragma unroll
    for (int i = 0; i < 4; ++i) {
      const u32 c  = (u32)dhS * 4 + i;                 // d-chunk 0..7
      const u32 ci = (c * 2 + par) ^ ((R & 7) << 1);
      *(uint4*)((char*)KS + R * 256 + ci * 16) = sk[i];
    }
    #pragma unroll
    for (int i = 0; i < 4; ++i) {
      const u32 ci = ((u32)kqS * 4 + i) ^ ((u32)dvS & 15);
      *(uint4*)((char*)VS + (u32)dvS * 256 + ci * 16) = sv[i];
    }
  };

  const int NT = qt + 1;               // 64-kv tiles
  const int NS = (NT + 1) >> 1;        // 128-kv supersteps

  issue(0);
  commit();
  __syncthreads();

  for (int s = 0; s < NS; ++s) {
    if (s + 1 < NS) issue(s + 1);      // global loads in flight during compute

    const int kb = (2 * s + p) * 64;   // this wave-pair's 64-kv tile
    if (kb <= qb) {
      const bool have1 = (kb + 32 <= qb);
      const bool dg0   = (kb == qb);
      const bool dg1   = (kb + 32 == qb);
      const int  kvb   = p * 64;       // base kv of this tile inside superstep

      f32x16 s0 = {}, s1 = {};
      __builtin_amdgcn_s_setprio(1);
      #pragma unroll
      for (int kk = 0; kk < 4; ++kk) {
        f16x8 kf = lds_fragK(KS, kvb + lo31, kk * 2 + hi);
        s0 = mfma16(kf, qf[kk], s0);
      }
      if (have1) {
        #pragma unroll
        for (int kk = 0; kk < 4; ++kk) {
          f16x8 kf = lds_fragK(KS, kvb + 32 + lo31, kk * 2 + hi);
          s1 = mfma16(kf, qf[kk], s1);
        }
      }
      __builtin_amdgcn_s_setprio(0);

      if (dg0) {
        #pragma unroll
        for (int i = 0; i < 16; ++i) {
          const int kvloc = (i & 3) + 8 * (i >> 2) + 4 * hi;
          if (kvloc > lo31) s0[i] = NEG_BIG;
        }
      }
      if (have1 && dg1) {
        #pragma unroll
        for (int i = 0; i < 16; ++i) {
          const int kvloc = (i & 3) + 8 * (i >> 2) + 4 * hi;
          if (kvloc > lo31) s1[i] = NEG_BIG;
        }
      }

      // --- 64-wide online softmax (lane pair l, l+32 = one q-row) ---
      float t8[8];
      #pragma unroll
      for (int i = 0; i < 8; ++i) t8[i] = fmaxf(s0[i], s0[i + 8]);
      if (have1) {
        #pragma unroll
        for (int i = 0; i < 8; ++i) t8[i] = fmaxf(t8[i], fmaxf(s1[i], s1[i + 8]));
      }
      float t4a = fmaxf(t8[0], t8[4]), t4b = fmaxf(t8[1], t8[5]);
      float t4c = fmaxf(t8[2], t8[6]), t4d = fmaxf(t8[3], t8[7]);
      float mt = fmaxf(fmaxf(t4a, t4b), fmaxf(t4c, t4d));
      mt = fmaxf(mt, __shfl_xor(mt, 32, 64));

      if (!__all(mt <= m_run + 8.0f)) {        // defer-max (T13)
        const float mn = fmaxf(m_run, mt);
        const float rs = __builtin_amdgcn_exp2f(m_run - mn);
        m_run = mn;
        r_sum *= rs;
        #pragma unroll
        for (int i = 0; i < 16; ++i) { o0[i] *= rs; o1[i] *= rs; }
      }

      float psum = 0.0f;
      u32 c0w[8], c1w[8];
      #pragma unroll
      for (int j = 0; j < 8; ++j) {
        float pa = __builtin_amdgcn_exp2f(s0[2 * j]     - m_run);
        float pb = __builtin_amdgcn_exp2f(s0[2 * j + 1] - m_run);
        psum += pa + pb;
        c0w[j] = pkrtz2(pa, pb);
      }
      if (have1) {
        #pragma unroll
        for (int j = 0; j < 8; ++j) {
          float pa = __builtin_amdgcn_exp2f(s1[2 * j]     - m_run);
          float pb = __builtin_amdgcn_exp2f(s1[2 * j + 1] - m_run);
          psum += pa + pb;
          c1w[j] = pkrtz2(pa, pb);
        }
      }
      psum += __shfl_xor(psum, 32, 64);
      r_sum += psum;

      // repack P (C/D layout) -> PV B-frags via permlane32_swap (T12)
      plswap(c0w[0], c0w[2]); plswap(c0w[1], c0w[3]);
      plswap(c0w[4], c0w[6]); plswap(c0w[5], c0w[7]);
      union { u32 u[4]; f16x8 v; } B0, B1;
      B0.u[0] = c0w[0]; B0.u[1] = c0w[1]; B0.u[2] = c0w[2]; B0.u[3] = c0w[3];
      B1.u[0] = c0w[4]; B1.u[1] = c0w[5]; B1.u[2] = c0w[6]; B1.u[3] = c0w[7];

      __builtin_amdgcn_s_setprio(1);
      #pragma unroll
      for (int ks = 0; ks < 2; ++ks) {
        const int kc = p * 8 + ks * 2 + hi;            // kv-chunk (sub 0)
        f16x8 va = lds_fragV(VS, lo31,      kc);
        f16x8 vb = lds_fragV(VS, 32 + lo31, kc);
        f16x8 pf = (ks == 0) ? B0.v : B1.v;
        o0 = mfma16(va, pf, o0);
        o1 = mfma16(vb, pf, o1);
      }
      __builtin_amdgcn_s_setprio(0);

      if (have1) {
        plswap(c1w[0], c1w[2]); plswap(c1w[1], c1w[3]);
        plswap(c1w[4], c1w[6]); plswap(c1w[5], c1w[7]);
        union { u32 u[4]; f16x8 v; } B2, B3;
        B2.u[0] = c1w[0]; B2.u[1] = c1w[1]; B2.u[2] = c1w[2]; B2.u[3] = c1w[3];
        B3.u[0] = c1w[4]; B3.u[1] = c1w[5]; B3.u[2] = c1w[6]; B3.u[3] = c1w[7];
        __builtin_amdgcn_s_setprio(1);
        #pragma unroll
        for (int ks = 0; ks < 2; ++ks) {
          const int kc = p * 8 + 4 + ks * 2 + hi;      // kv-chunk (sub 1)
          f16x8 va = lds_fragV(VS, lo31,      kc);
          f16x8 vb = lds_fragV(VS, 32 + lo31, kc);
          f16x8 pf = (ks == 0) ? B2.v : B3.v;
          o0 = mfma16(va, pf, o0);
          o1 = mfma16(vb, pf, o1);
        }
        __builtin_amdgcn_s_setprio(0);
      }
    }

    __syncthreads();                   // all waves done reading LDS
    if (s + 1 < NS) { commit(); __syncthreads(); }
  }

  // ---- merge kv-parity partials: p=1 waves -> LDS, p=0 waves merge+store ----
  const int l64 = t & 63;
  if (p == 1) {
    float* mb = (float*)((w == 2) ? (void*)KS : (void*)VS);
    #pragma unroll
    for (int i = 0; i < 16; ++i) mb[i * 64 + l64] = o0[i];
    #pragma unroll
    for (int i = 0; i < 16; ++i) mb[(16 + i) * 64 + l64] = o1[i];
    mb[32 * 64 + l64] = m_run;
    mb[33 * 64 + l64] = r_sum;
  }
  __syncthreads();
  if (p == 0) {
    const float* mb = (const float*)((w == 0) ? (void*)KS : (void*)VS);
    const float m_b = mb[32 * 64 + l64];
    const float r_b = mb[33 * 64 + l64];
    const float mn  = fmaxf(m_run, m_b);
    const float sa  = __builtin_amdgcn_exp2f(m_run - mn);
    const float sb  = __builtin_amdgcn_exp2f(m_b  - mn);
    const float inv = 1.0f / (r_sum * sa + r_b * sb);
    float* op = Out + ((size_t)bh * S_LEN + qb + lo31) * D_DIM;
    #pragma unroll
    for (int g = 0; g < 4; ++g) {
      float4 s0v, s1v;
      #pragma unroll
      for (int k = 0; k < 4; ++k) {
        const int i = 4 * g + k;
        ((float*)&s0v)[k] = (o0[i] * sa + mb[i * 64 + l64]        * sb) * inv;
        ((float*)&s1v)[k] = (o1[i] * sa + mb[(16 + i) * 64 + l64] * sb) * inv;
      }
      *(float4*)(op + g * 8 + hi * 4)      = s0v;   // dv = 8g + 4*hi + 0..3
      *(float4*)(op + 32 + g * 8 + hi * 4) = s1v;   // dv + 32
    }
  }
}

extern "C" void kernel_launch(void* const* d_in, const int* in_sizes, int n_in,
                              void* d_out, int out_size, void* d_ws, size_t ws_size,
                              hipStream_t stream) {
  const float* Q = (const float*)d_in[0];
  const float* K = (const float*)d_in[1];
  const float* V = (const float*)d_in[2];
  // d_in[3] = tril mask: handled analytically (causal), not read.
  float* Out = (float*)d_out;
  u16* Vt = (u16*)d_ws;                                   // 8.39 MB
  u16* Kt = (u16*)d_ws + (size_t)BH_N * S_LEN * D_DIM;    // +8.39 MB
  prep_kernel<<<dim3(BH_N * (S_LEN / 64)), dim3(256), 0, stream>>>(K, V, Kt, Vt);
  attn_kernel<<<dim3(BH_N * 32), dim3(256), 0, stream>>>(Q, Kt, Vt, Out);
}

// Round 8
// 143.960 us; speedup vs baseline: 2.0147x; 1.5210x over previous
//
#include <hip/hip_runtime.h>

// Causal attention fwd, B=2 H=16 S=2048 DK=DV=64, fp32 in/out.
// R8 = R6/R7 resubmit (infra failures, never executed). Prep kernel writes,
// per (bh, 128-kv superstep), a 32KB pre-swizzled f16 "LDS image"
// {K 16KB, V^T 16KB} in d_ws. Attn stages it with global_load_lds (16B async,
// zero staging VGPRs) into double-buffered 2x32KB LDS: issue s+1 ->
// compute s -> vmcnt(0)+barrier.
// Compute structure from R5 (passed, absmax 0.0156): 4 waves = 2 q-subtiles
// x 2 kv-parities, swapped QK^T, 64-wide online softmax, defer-max,
// permlane32_swap repack, end-of-block merge.

#define S_LEN   2048
#define D_DIM   64
#define BH_N    32
#define NEG_BIG (-3.0e38f)
#define CSCALE  0.18033688011112042f   // log2(e)/sqrt(64)

typedef float     f32x16 __attribute__((ext_vector_type(16)));
typedef _Float16  f16x8  __attribute__((ext_vector_type(8)));
typedef __fp16    fp16x2 __attribute__((ext_vector_type(2)));
typedef unsigned int   u32;
typedef unsigned short u16;

__device__ __forceinline__ u32 pkrtz2(float a, float b) {
  union { fp16x2 h; u32 u; } U;
  U.h = __builtin_amdgcn_cvt_pkrtz(a, b);
  return U.u;
}

__device__ __forceinline__ void plswap(u32& a, u32& b) {
  auto r = __builtin_amdgcn_permlane32_swap((int)a, (int)b, false, false);
  a = (u32)r[0]; b = (u32)r[1];
}

__device__ __forceinline__ f32x16 mfma16(f16x8 a, f16x8 b, f32x16 c) {
  return __builtin_amdgcn_mfma_f32_32x32x16_f16(a, b, c, 0, 0, 0);
}

// async 16B global->LDS (wave-uniform LDS base, per-lane global addr)
__device__ __forceinline__ void gload_lds16(const void* g, void* l) {
  __builtin_amdgcn_global_load_lds(
      (const __attribute__((address_space(1))) u32*)g,
      (__attribute__((address_space(3))) u32*)l, 16, 0, 0);
}

// K image: 128 kv x 64 d f16. 256B rows = kv pair (2R,2R+1).
// chunk ci = (dchunk*2 + (kv&1)) ^ ((R&7)<<1) -> octet-conflict-free.
__device__ __forceinline__ f16x8 lds_fragK(const u16* base, int kv, int dchunk) {
  const u32 R  = (u32)kv >> 1;
  const u32 ci = ((u32)dchunk * 2 + ((u32)kv & 1)) ^ ((R & 7) << 1);
  return *(const f16x8*)((const char*)base + R * 256 + ci * 16);
}
// V^T image: 64 dv x 128 kv f16, 256B rows. chunk ci = kvchunk ^ (dv&15).
__device__ __forceinline__ f16x8 lds_fragV(const u16* base, int dv, int kvchunk) {
  const u32 ci = (u32)kvchunk ^ ((u32)dv & 15);
  return *(const f16x8*)((const char*)base + (u32)dv * 256 + ci * 16);
}

// ---- prep: build 32KB pre-swizzled image per (bh, superstep) in d_ws ----
// img[(bh*16+s)] : bytes [0,16K) = K image, [16K,32K) = V^T image.
__global__ __launch_bounds__(256) void prep_kernel(const float* __restrict__ K,
                                                   const float* __restrict__ V,
                                                   u16* __restrict__ img) {
  __shared__ __align__(16) float vbuf[128 * 64];   // 32KB, chunk-swizzled
  const int bid  = blockIdx.x;         // 512 = 32 bh * 16 supersteps
  const int bh   = bid & 31;
  const int sidx = bid >> 5;
  const int kb   = sidx * 128;
  const int t    = threadIdx.x;
  const int kvS  = t & 127;
  const int dh   = t >> 7;             // which 32-d half
  char* ib = (char*)img + ((size_t)(bh * 16 + sidx)) * 32768;

  { // K -> K image (cvt f32->f16, swizzled chunk positions)
    const float* kg = K + ((size_t)bh * S_LEN + kb + kvS) * D_DIM + dh * 32;
    float fv[32];
    #pragma unroll
    for (int i = 0; i < 8; ++i) {
      float4 a = *(const float4*)(kg + 4 * i);
      fv[4 * i + 0] = a.x; fv[4 * i + 1] = a.y;
      fv[4 * i + 2] = a.z; fv[4 * i + 3] = a.w;
    }
    const u32 R = (u32)kvS >> 1, par = (u32)kvS & 1;
    #pragma unroll
    for (int c = 0; c < 4; ++c) {
      uint4 d = make_uint4(pkrtz2(fv[8*c+0], fv[8*c+1]), pkrtz2(fv[8*c+2], fv[8*c+3]),
                           pkrtz2(fv[8*c+4], fv[8*c+5]), pkrtz2(fv[8*c+6], fv[8*c+7]));
      const u32 dchunk = (u32)dh * 4 + c;
      const u32 ci = (dchunk * 2 + par) ^ ((R & 7) << 1);
      *(uint4*)(ib + R * 256 + ci * 16) = d;
    }
  }
  { // V -> LDS f32 (chunk-swizzled rows for conflict-free column reads)
    const float* vg = V + ((size_t)bh * S_LEN + kb + kvS) * D_DIM + dh * 32;
    #pragma unroll
    for (int i = 0; i < 8; ++i) {
      float4 a = *(const float4*)(vg + 4 * i);
      const u32 c4 = (u32)dh * 8 + i;
      *(float4*)((char*)vbuf + kvS * 256 + ((c4 ^ ((u32)kvS & 15)) * 16)) = a;
    }
  }
  __syncthreads();
  { // LDS -> V^T image (transpose + cvt, swizzled chunk positions)
    const int dv = t & 63, kq = t >> 6;
    u32 wv[16];
    #pragma unroll
    for (int j = 0; j < 16; ++j) {
      const int k0 = kq * 32 + 2 * j, k1 = k0 + 1;
      float f0 = *(const float*)((char*)vbuf + k0 * 256 +
                  ((((u32)dv >> 2) ^ ((u32)k0 & 15)) * 16) + (dv & 3) * 4);
      float f1 = *(const float*)((char*)vbuf + k1 * 256 +
                  ((((u32)dv >> 2) ^ ((u32)k1 & 15)) * 16) + (dv & 3) * 4);
      wv[j] = pkrtz2(f0, f1);
    }
    #pragma unroll
    for (int x = 0; x < 4; ++x) {
      const u32 kvc = (u32)kq * 4 + x;
      const u32 ci  = kvc ^ ((u32)dv & 15);
      *(uint4*)(ib + 16384 + dv * 256 + ci * 16) =
          make_uint4(wv[4*x+0], wv[4*x+1], wv[4*x+2], wv[4*x+3]);
    }
  }
}

// ---------------- main flash attention ----------------
__global__ __launch_bounds__(256, 2) void attn_kernel(const float* __restrict__ Q,
                                                      const u16* __restrict__ img,
                                                      float* __restrict__ Out) {
  __shared__ __align__(16) u16 IMG[2][16384];   // 2 x 32KB double buffer

  const int bid = blockIdx.x;          // 1024 = 32 bh * 32 qt
  const int bh  = bid & 31;
  const int qt  = 31 - (bid >> 5);     // biggest causal jobs first
  const int t   = threadIdx.x;
  const int w   = t >> 6;
  const int l   = t & 63;
  const int lo31 = t & 31;
  const int hi  = (t >> 5) & 1;
  const int p   = w >> 1;              // kv parity: waves 0,1 even; 2,3 odd
  const int qb  = qt * 64 + (w & 1) * 32;

  // Q fragment (f16, scale folded): col=q=lane&31, k=d = kk*16 + hi*8 + j
  f16x8 qf[4];
  {
    const float* qp = Q + ((size_t)bh * S_LEN + qb + lo31) * D_DIM;
    #pragma unroll
    for (int kk = 0; kk < 4; ++kk) {
      const int dd = kk * 16 + hi * 8;
      float4 a = *(const float4*)(qp + dd);
      float4 b = *(const float4*)(qp + dd + 4);
      union { u32 u[4]; f16x8 v; } U;
      U.u[0] = pkrtz2(a.x * CSCALE, a.y * CSCALE);
      U.u[1] = pkrtz2(a.z * CSCALE, a.w * CSCALE);
      U.u[2] = pkrtz2(b.x * CSCALE, b.y * CSCALE);
      U.u[3] = pkrtz2(b.z * CSCALE, b.w * CSCALE);
      qf[kk] = U.v;
    }
  }

  f32x16 o0 = {};      // O^T rows dv 0..31 (col=q, row=(i&3)+8*(i>>2)+4*hi)
  f32x16 o1 = {};      // O^T rows dv 32..63
  float m_run = NEG_BIG;
  float r_sum = 0.0f;

  const char* gimg = (const char*)img + (size_t)bh * (16 * 32768);
  auto issue = [&](int s, int b) {     // wave w stages bytes [w*8K, w*8K+8K)
    const char* g = gimg + (size_t)s * 32768 + (u32)(w * 8192) + (u32)(l * 16);
    char* lp = (char*)&IMG[b][0] + w * 8192;       // wave-uniform LDS base
    #pragma unroll
    for (int j = 0; j < 8; ++j)
      gload_lds16(g + j * 1024, lp + j * 1024);
  };

  const int NT = qt + 1;               // 64-kv tiles
  const int NS = (NT + 1) >> 1;        // 128-kv supersteps

  issue(0, 0);
  asm volatile("s_waitcnt vmcnt(0)" ::: "memory");
  __syncthreads();

  for (int s = 0; s < NS; ++s) {
    const int cur = s & 1;
    if (s + 1 < NS) issue(s + 1, cur ^ 1);   // async loads fly under compute

    const int kb = (2 * s + p) * 64;         // this wave-pair's 64-kv tile
    if (kb <= qb) {
      const u16* KSb = &IMG[cur][0];
      const u16* VSb = &IMG[cur][8192];
      const bool have1 = (kb + 32 <= qb);
      const bool dg0   = (kb == qb);
      const bool dg1   = (kb + 32 == qb);
      const int  kvb   = p * 64;

      f32x16 s0 = {}, s1 = {};
      __builtin_amdgcn_s_setprio(1);
      #pragma unroll
      for (int kk = 0; kk < 4; ++kk) {
        f16x8 kf = lds_fragK(KSb, kvb + lo31, kk * 2 + hi);
        s0 = mfma16(kf, qf[kk], s0);
      }
      if (have1) {
        #pragma unroll
        for (int kk = 0; kk < 4; ++kk) {
          f16x8 kf = lds_fragK(KSb, kvb + 32 + lo31, kk * 2 + hi);
          s1 = mfma16(kf, qf[kk], s1);
        }
      }
      __builtin_amdgcn_s_setprio(0);

      if (dg0) {
        #pragma unroll
        for (int i = 0; i < 16; ++i) {
          const int kvloc = (i & 3) + 8 * (i >> 2) + 4 * hi;
          if (kvloc > lo31) s0[i] = NEG_BIG;
        }
      }
      if (have1 && dg1) {
        #pragma unroll
        for (int i = 0; i < 16; ++i) {
          const int kvloc = (i & 3) + 8 * (i >> 2) + 4 * hi;
          if (kvloc > lo31) s1[i] = NEG_BIG;
        }
      }

      // --- 64-wide online softmax (lane pair l, l+32 = one q-row) ---
      float t8[8];
      #pragma unroll
      for (int i = 0; i < 8; ++i) t8[i] = fmaxf(s0[i], s0[i + 8]);
      if (have1) {
        #pragma unroll
        for (int i = 0; i < 8; ++i) t8[i] = fmaxf(t8[i], fmaxf(s1[i], s1[i + 8]));
      }
      float t4a = fmaxf(t8[0], t8[4]), t4b = fmaxf(t8[1], t8[5]);
      float t4c = fmaxf(t8[2], t8[6]), t4d = fmaxf(t8[3], t8[7]);
      float mt = fmaxf(fmaxf(t4a, t4b), fmaxf(t4c, t4d));
      mt = fmaxf(mt, __shfl_xor(mt, 32, 64));

      if (!__all(mt <= m_run + 8.0f)) {        // defer-max (T13)
        const float mn = fmaxf(m_run, mt);
        const float rs = __builtin_amdgcn_exp2f(m_run - mn);
        m_run = mn;
        r_sum *= rs;
        #pragma unroll
        for (int i = 0; i < 16; ++i) { o0[i] *= rs; o1[i] *= rs; }
      }

      float psum = 0.0f;
      u32 c0w[8], c1w[8];
      #pragma unroll
      for (int j = 0; j < 8; ++j) {
        float pa = __builtin_amdgcn_exp2f(s0[2 * j]     - m_run);
        float pb = __builtin_amdgcn_exp2f(s0[2 * j + 1] - m_run);
        psum += pa + pb;
        c0w[j] = pkrtz2(pa, pb);
      }
      if (have1) {
        #pragma unroll
        for (int j = 0; j < 8; ++j) {
          float pa = __builtin_amdgcn_exp2f(s1[2 * j]     - m_run);
          float pb = __builtin_amdgcn_exp2f(s1[2 * j + 1] - m_run);
          psum += pa + pb;
          c1w[j] = pkrtz2(pa, pb);
        }
      }
      psum += __shfl_xor(psum, 32, 64);
      r_sum += psum;

      // repack P (C/D layout) -> PV B-frags via permlane32_swap (T12)
      plswap(c0w[0], c0w[2]); plswap(c0w[1], c0w[3]);
      plswap(c0w[4], c0w[6]); plswap(c0w[5], c0w[7]);
      union { u32 u[4]; f16x8 v; } B0, B1;
      B0.u[0] = c0w[0]; B0.u[1] = c0w[1]; B0.u[2] = c0w[2]; B0.u[3] = c0w[3];
      B1.u[0] = c0w[4]; B1.u[1] = c0w[5]; B1.u[2] = c0w[6]; B1.u[3] = c0w[7];

      __builtin_amdgcn_s_setprio(1);
      #pragma unroll
      for (int ks = 0; ks < 2; ++ks) {
        const int kc = p * 8 + ks * 2 + hi;
        f16x8 va = lds_fragV(VSb, lo31,      kc);
        f16x8 vb = lds_fragV(VSb, 32 + lo31, kc);
        f16x8 pf = (ks == 0) ? B0.v : B1.v;
        o0 = mfma16(va, pf, o0);
        o1 = mfma16(vb, pf, o1);
      }
      __builtin_amdgcn_s_setprio(0);

      if (have1) {
        plswap(c1w[0], c1w[2]); plswap(c1w[1], c1w[3]);
        plswap(c1w[4], c1w[6]); plswap(c1w[5], c1w[7]);
        union { u32 u[4]; f16x8 v; } B2, B3;
        B2.u[0] = c1w[0]; B2.u[1] = c1w[1]; B2.u[2] = c1w[2]; B2.u[3] = c1w[3];
        B3.u[0] = c1w[4]; B3.u[1] = c1w[5]; B3.u[2] = c1w[6]; B3.u[3] = c1w[7];
        __builtin_amdgcn_s_setprio(1);
        #pragma unroll
        for (int ks = 0; ks < 2; ++ks) {
          const int kc = p * 8 + 4 + ks * 2 + hi;
          f16x8 va = lds_fragV(VSb, lo31,      kc);
          f16x8 vb = lds_fragV(VSb, 32 + lo31, kc);
          f16x8 pf = (ks == 0) ? B2.v : B3.v;
          o0 = mfma16(va, pf, o0);
          o1 = mfma16(vb, pf, o1);
        }
        __builtin_amdgcn_s_setprio(0);
      }
    }

    asm volatile("s_waitcnt vmcnt(0)" ::: "memory");   // own DMA landed
    __syncthreads();                                   // everyone's landed
  }

  // ---- merge kv-parity partials: p=1 waves -> LDS, p=0 waves merge+store ----
  const int l64 = t & 63;
  float* mbase = (float*)&IMG[0][0];
  if (p == 1) {
    float* mb = mbase + (w & 1) * (34 * 64);
    #pragma unroll
    for (int i = 0; i < 16; ++i) mb[i * 64 + l64] = o0[i];
    #pragma unroll
    for (int i = 0; i < 16; ++i) mb[(16 + i) * 64 + l64] = o1[i];
    mb[32 * 64 + l64] = m_run;
    mb[33 * 64 + l64] = r_sum;
  }
  __syncthreads();
  if (p == 0) {
    const float* mb = mbase + (w & 1) * (34 * 64);
    const float m_b = mb[32 * 64 + l64];
    const float r_b = mb[33 * 64 + l64];
    const float mn  = fmaxf(m_run, m_b);
    const float sa  = __builtin_amdgcn_exp2f(m_run - mn);
    const float sb  = __builtin_amdgcn_exp2f(m_b  - mn);
    const float inv = 1.0f / (r_sum * sa + r_b * sb);
    float* op = Out + ((size_t)bh * S_LEN + qb + lo31) * D_DIM;
    #pragma unroll
    for (int g = 0; g < 4; ++g) {
      float4 s0v, s1v;
      #pragma unroll
      for (int k = 0; k < 4; ++k) {
        const int i = 4 * g + k;
        ((float*)&s0v)[k] = (o0[i] * sa + mb[i * 64 + l64]        * sb) * inv;
        ((float*)&s1v)[k] = (o1[i] * sa + mb[(16 + i) * 64 + l64] * sb) * inv;
      }
      *(float4*)(op + g * 8 + hi * 4)      = s0v;   // dv = 8g + 4*hi + 0..3
      *(float4*)(op + 32 + g * 8 + hi * 4) = s1v;   // dv + 32
    }
  }
}

extern "C" void kernel_launch(void* const* d_in, const int* in_sizes, int n_in,
                              void* d_out, int out_size, void* d_ws, size_t ws_size,
                              hipStream_t stream) {
  const float* Q = (const float*)d_in[0];
  const float* K = (const float*)d_in[1];
  const float* V = (const float*)d_in[2];
  // d_in[3] = tril mask: handled analytically (causal), not read.
  float* Out = (float*)d_out;
  u16* img = (u16*)d_ws;               // 32 bh * 16 supersteps * 32KB = 16 MB
  prep_kernel<<<dim3(BH_N * 16), dim3(256), 0, stream>>>(K, V, img);
  attn_kernel<<<dim3(BH_N * 32), dim3(256), 0, stream>>>(Q, img, Out);
}